// Round 3
// baseline (289.813 us; speedup 1.0000x reference)
//
#include <hip/hip_runtime.h>

#define HID 128
#define CLS 10
#define NW 4      // source windows (each ~N/4 nodes * 256B = 3.2MB, fits 4MiB per-XCD L2)
#define BCAP 24   // per-bucket CSR capacity; deg/window ~ Poisson(3), P(>24) ~ 1e-15
#define NSTR (NW * BCAP)  // 96 ints per node

typedef short short8 __attribute__((ext_vector_type(8)));
typedef float f32x4 __attribute__((ext_vector_type(4)));

// float -> bf16 round-to-nearest-even
__device__ __forceinline__ unsigned short f2bf(float f) {
  union { float f; unsigned u; } v; v.f = f;
  unsigned u = v.u;
  return (unsigned short)((u + 0x7FFFu + ((u >> 16) & 1u)) >> 16);
}
__device__ __forceinline__ float bf_lo(unsigned p) { return __uint_as_float(p << 16); }
__device__ __forceinline__ float bf_hi(unsigned p) { return __uint_as_float(p & 0xFFFF0000u); }

// ---------------- setup: zero degw + pooled + Tb zero-row, build Wt ----------------

__global__ __launch_bounds__(256) void zero_wt(int* __restrict__ degw, int n, int nbN,
                                               float* __restrict__ pooled, int gh,
                                               const float* __restrict__ W1,
                                               const float* __restrict__ W2,
                                               const float* __restrict__ W3,
                                               unsigned short* __restrict__ Wt,
                                               unsigned short* __restrict__ TbZeroRow) {
  int b = blockIdx.x;
  if (b < nbN) {
    int i = b * 256 + threadIdx.x;
    if (i < n) { int4 z4; z4.x = z4.y = z4.z = z4.w = 0; *(int4*)&degw[(size_t)i * 4] = z4; }
    if (i < gh) pooled[i] = 0.f;
    if (b == 0 && threadIdx.x < 16) {  // zero the dummy row (index N) of Tb: 256 B
      uint4 z; z.x = z.y = z.z = z.w = 0u;
      *(uint4*)&TbZeroRow[threadIdx.x * 8] = z;
    }
    return;
  }
  int wb = b - nbN;                  // 0..47
  int mat = wb >> 4;                 // 0..2
  int part = wb & 15;                // 0..15
  const float* W = (mat == 0) ? W1 : (mat == 1) ? W2 : W3;
  unsigned short* o = Wt + (size_t)mat * HID * HID;
  int base = part * (HID * HID / 16);
  for (int r = 0; r < HID * HID / 16; r += 256) {
    int idx = base + r + threadIdx.x;
    int k = idx >> 7, nn = idx & 127;
    o[nn * HID + k] = f2bf(W[idx]);   // Wt[n][k] = W[k][n]
  }
}

// degree histogram (per source-window bucket) + bucketed padded-CSR fill in one pass
__global__ __launch_bounds__(256) void degree_fill(const int* __restrict__ src,
                                                   const int* __restrict__ dst,
                                                   int* __restrict__ degw,
                                                   int* __restrict__ col_src, int E,
                                                   float wscale) {
  int e = blockIdx.x * 256 + threadIdx.x;
  if (e >= E) return;
  int s = src[e];
  int d = dst[e];
  int w = (int)((float)s * wscale);
  if (w > NW - 1) w = NW - 1;
  int slot = atomicAdd(&degw[(size_t)d * 4 + w], 1);
  if (slot < BCAP) col_src[(size_t)d * NSTR + w * BCAP + slot] = s;
}

// ---------------- MFMA bf16 GEMM: Tb[r,:] = bf16( dinv[r] * (A[r,:] @ W) ) ----------------
// Block = 4 waves x 32 rows = 128 rows. W staged in LDS; A fragments direct
// global->VGPR. a_fp32=1: layer 1 reads fp32 x, converts in-register.
// pad_col != nullptr (layer 1 only): pad each CSR bucket to a multiple of 4
// with dummy index `nrows` (the zero row), so aggregate loops have no scalar tail.

#define WTP 136  // 128 + 8 pad

__global__ __launch_bounds__(256) void gemm_mfma(const void* __restrict__ Aptr,
                                                 int a_fp32,
                                                 const unsigned short* __restrict__ Wt,  // bf16 [n][k]
                                                 const int* __restrict__ degw,
                                                 unsigned short* __restrict__ Tb,  // bf16 [n][128]
                                                 int* __restrict__ pad_col,
                                                 int nrows) {
  __shared__ unsigned short sW[HID][WTP];
  int tid = threadIdx.x;
  int wave = tid >> 6, lane = tid & 63;
  int m_lo = lane & 15, quad = lane >> 4;
  int row0 = blockIdx.x * 128;
  int rbase = row0 + wave * 32;

  uint4 araw[2][4];
#pragma unroll
  for (int tr = 0; tr < 2; ++tr) {
    int grow = rbase + tr * 16 + m_lo;
    int gr = (grow < nrows) ? grow : (nrows - 1);  // clamp: stores guarded later
    if (a_fp32) {
      const float* Arow = (const float*)Aptr + (size_t)gr * HID;
#pragma unroll
      for (int kb = 0; kb < 4; ++kb) {
        float4 f0 = *(const float4*)&Arow[kb * 32 + quad * 8];
        float4 f1 = *(const float4*)&Arow[kb * 32 + quad * 8 + 4];
        uint4 u;
        u.x = (unsigned)f2bf(f0.x) | ((unsigned)f2bf(f0.y) << 16);
        u.y = (unsigned)f2bf(f0.z) | ((unsigned)f2bf(f0.w) << 16);
        u.z = (unsigned)f2bf(f1.x) | ((unsigned)f2bf(f1.y) << 16);
        u.w = (unsigned)f2bf(f1.z) | ((unsigned)f2bf(f1.w) << 16);
        araw[tr][kb] = u;
      }
    } else {
      const uint4* Arow = (const uint4*)((const unsigned*)Aptr + (size_t)gr * 64);
#pragma unroll
      for (int kb = 0; kb < 4; ++kb) araw[tr][kb] = Arow[kb * 4 + quad];
    }
  }

  const uint4* Wt4 = (const uint4*)Wt;
#pragma unroll
  for (int i = 0; i < 8; ++i) {
    int idx = i * 256 + tid;
    *(uint4*)&sW[idx >> 4][(idx & 15) * 8] = Wt4[idx];
  }
  __syncthreads();

  f32x4 acc[2][8];
#pragma unroll
  for (int tr = 0; tr < 2; ++tr)
#pragma unroll
    for (int tc = 0; tc < 8; ++tc) acc[tr][tc] = (f32x4)(0.f);

#pragma unroll
  for (int kb = 0; kb < 4; ++kb) {
    short8 b[8];
#pragma unroll
    for (int tc = 0; tc < 8; ++tc) {
      union { uint4 u; short8 s; } cv;
      cv.u = *(const uint4*)&sW[tc * 16 + m_lo][kb * 32 + quad * 8];
      b[tc] = cv.s;
    }
#pragma unroll
    for (int tr = 0; tr < 2; ++tr) {
      union { uint4 u; short8 s; } av;
      av.u = araw[tr][kb];
#pragma unroll
      for (int tc = 0; tc < 8; ++tc)
        acc[tr][tc] = __builtin_amdgcn_mfma_f32_16x16x32_bf16(av.s, b[tc], acc[tr][tc], 0, 0, 0);
    }
  }

#pragma unroll
  for (int tr = 0; tr < 2; ++tr) {
#pragma unroll
    for (int r = 0; r < 4; ++r) {
      int grow = rbase + tr * 16 + quad * 4 + r;
      if (grow < nrows) {
        int4 cwv = *(const int4*)&degw[(size_t)grow * 4];
        int dgv = cwv.x + cwv.y + cwv.z + cwv.w;
        float s = rsqrtf((float)dgv + 1.0f);  // dinv inline
        unsigned short* orow = &Tb[(size_t)grow * HID];
#pragma unroll
        for (int tc = 0; tc < 8; ++tc)
          orow[tc * 16 + m_lo] = f2bf(s * acc[tr][tc][r]);
        if (pad_col && m_lo == 0) {
#pragma unroll
          for (int w = 0; w < NW; ++w) {
            int cc = (w == 0) ? cwv.x : (w == 1) ? cwv.y : (w == 2) ? cwv.z : cwv.w;
            int d = cc < BCAP ? cc : BCAP;
            int dp = (d + 3) & ~3;
            for (int sl = d; sl < dp; ++sl)
              pad_col[(size_t)grow * NSTR + w * BCAP + sl] = nrows;  // dummy -> zero row
          }
        }
      }
    }
  }
}

// ---------------- aggregate core: window-phased, 4 nodes per 16-lane group ----------------
// Each block owns 64 consecutive nodes (16 groups x 4 nodes). All blocks sweep
// source windows w=0..3 in the same order, so gathers concentrate in a ~3.2MB
// Tb window that stays resident in each XCD's 4MiB L2. Node pairs are processed
// together -> 8 gathers in flight per group (32 per wave). Pad/dummy gathers hit
// the L1-hot zero row and do not consume L2-miss slots.

__device__ __forceinline__ void accum_row(float a[8], uint4 v) {
  a[0] += bf_lo(v.x); a[1] += bf_hi(v.x);
  a[2] += bf_lo(v.y); a[3] += bf_hi(v.y);
  a[4] += bf_lo(v.z); a[5] += bf_hi(v.z);
  a[6] += bf_lo(v.w); a[7] += bf_hi(v.w);
}

__device__ __forceinline__ uint4 tb_row(const unsigned* __restrict__ Tb2, int idx, int l4) {
  return *(const uint4*)&Tb2[(size_t)idx * 64 + l4 * 4];
}

__device__ __forceinline__ int cw_get(int4 v, int w) {
  return (w == 0) ? v.x : (w == 1) ? v.y : (w == 2) ? v.z : v.w;
}

__device__ __forceinline__ void agg_quad(const unsigned* __restrict__ Tb2,
                                         const int* __restrict__ col_src,
                                         const int4 cw[4], const int nd[4], int l4,
                                         int nzero, float acc[4][8]) {
#pragma unroll
  for (int c = 0; c < 4; ++c) {  // self-loop rows (init accumulators)
    uint4 sv = tb_row(Tb2, nd[c], l4);
    acc[c][0] = bf_lo(sv.x); acc[c][1] = bf_hi(sv.x);
    acc[c][2] = bf_lo(sv.y); acc[c][3] = bf_hi(sv.y);
    acc[c][4] = bf_lo(sv.z); acc[c][5] = bf_hi(sv.z);
    acc[c][6] = bf_lo(sv.w); acc[c][7] = bf_hi(sv.w);
  }
#pragma unroll
  for (int w = 0; w < NW; ++w) {
#pragma unroll
    for (int cp = 0; cp < 2; ++cp) {
      const int c0 = cp * 2, c1 = cp * 2 + 1;
      int n0 = cw_get(cw[c0], w); n0 = n0 < BCAP ? n0 : BCAP;
      int n1 = cw_get(cw[c1], w); n1 = n1 < BCAP ? n1 : BCAP;
      int dp0 = (n0 + 3) & ~3, dp1 = (n1 + 3) & ~3;
      const int* r0 = &col_src[(size_t)nd[c0] * NSTR + w * BCAP];
      const int* r1 = &col_src[(size_t)nd[c1] * NSTR + w * BCAP];
      int4 i0 = (dp0 > 0) ? *(const int4*)r0 : make_int4(nzero, nzero, nzero, nzero);
      int4 i1 = (dp1 > 0) ? *(const int4*)r1 : make_int4(nzero, nzero, nzero, nzero);
      uint4 v0[4], v1[4];
      v0[0] = tb_row(Tb2, i0.x, l4); v0[1] = tb_row(Tb2, i0.y, l4);
      v0[2] = tb_row(Tb2, i0.z, l4); v0[3] = tb_row(Tb2, i0.w, l4);
      v1[0] = tb_row(Tb2, i1.x, l4); v1[1] = tb_row(Tb2, i1.y, l4);
      v1[2] = tb_row(Tb2, i1.z, l4); v1[3] = tb_row(Tb2, i1.w, l4);
#pragma unroll
      for (int u = 0; u < 4; ++u) accum_row(acc[c0], v0[u]);
#pragma unroll
      for (int u = 0; u < 4; ++u) accum_row(acc[c1], v1[u]);
      for (int j = 4; j < dp0; j += 4) {  // rare: bucket count > 4
        int4 ii = *(const int4*)(r0 + j);
        uint4 a0 = tb_row(Tb2, ii.x, l4), a1 = tb_row(Tb2, ii.y, l4);
        uint4 a2 = tb_row(Tb2, ii.z, l4), a3 = tb_row(Tb2, ii.w, l4);
        accum_row(acc[c0], a0); accum_row(acc[c0], a1);
        accum_row(acc[c0], a2); accum_row(acc[c0], a3);
      }
      for (int j = 4; j < dp1; j += 4) {
        int4 ii = *(const int4*)(r1 + j);
        uint4 a0 = tb_row(Tb2, ii.x, l4), a1 = tb_row(Tb2, ii.y, l4);
        uint4 a2 = tb_row(Tb2, ii.z, l4), a3 = tb_row(Tb2, ii.w, l4);
        accum_row(acc[c1], a0); accum_row(acc[c1], a1);
        accum_row(acc[c1], a2); accum_row(acc[c1], a3);
      }
    }
  }
}

// layers 1,2: write packed bf16 H (consumed by next GEMM); nontemporal stores so
// the 12.8MB output stream does not evict the L2-resident source window.
__global__ __launch_bounds__(256) void aggregate(const unsigned* __restrict__ Tb2,
                                                 const int* __restrict__ degw,
                                                 const int* __restrict__ col_src,
                                                 const float* __restrict__ bias,
                                                 unsigned* __restrict__ Hb, int n, int nzero) {
  int tid = threadIdx.x;
  int g = tid >> 4, l4 = tid & 15;
  int base = blockIdx.x * 64 + g * 4;
  int nd[4]; int4 cw[4];
#pragma unroll
  for (int c = 0; c < 4; ++c) {
    int node = base + c;
    nd[c] = node < n ? node : (n - 1);
    cw[c] = *(const int4*)&degw[(size_t)nd[c] * 4];
  }
  float acc[4][8];
  agg_quad(Tb2, col_src, cw, nd, l4, nzero, acc);

  float4 bs0 = *(const float4*)&bias[l4 * 8];
  float4 bs1 = *(const float4*)&bias[l4 * 8 + 4];
#pragma unroll
  for (int c = 0; c < 4; ++c) {
    int node = base + c;
    if (node < n) {
      int deg = cw[c].x + cw[c].y + cw[c].z + cw[c].w;
      float di = rsqrtf((float)deg + 1.0f);
      float o0 = fmaxf(di * acc[c][0] + bs0.x, 0.f);
      float o1 = fmaxf(di * acc[c][1] + bs0.y, 0.f);
      float o2 = fmaxf(di * acc[c][2] + bs0.z, 0.f);
      float o3 = fmaxf(di * acc[c][3] + bs0.w, 0.f);
      float o4 = fmaxf(di * acc[c][4] + bs1.x, 0.f);
      float o5 = fmaxf(di * acc[c][5] + bs1.y, 0.f);
      float o6 = fmaxf(di * acc[c][6] + bs1.z, 0.f);
      float o7 = fmaxf(di * acc[c][7] + bs1.w, 0.f);
      union { uint4 u4; unsigned long long ll[2]; } o;
      o.u4.x = (unsigned)f2bf(o0) | ((unsigned)f2bf(o1) << 16);
      o.u4.y = (unsigned)f2bf(o2) | ((unsigned)f2bf(o3) << 16);
      o.u4.z = (unsigned)f2bf(o4) | ((unsigned)f2bf(o5) << 16);
      o.u4.w = (unsigned)f2bf(o6) | ((unsigned)f2bf(o7) << 16);
      unsigned long long* dst = (unsigned long long*)&Hb[(size_t)node * 64 + l4 * 4];
      __builtin_nontemporal_store(o.ll[0], dst);
      __builtin_nontemporal_store(o.ll[1], dst + 1);
    }
  }
}

// layer 3: no Hb output; pool directly (block = 64 consecutive nodes, run-detected
// atomics into pooled; scan split across two 128-lane halves)
#define SPP 132  // 128 + 4 pad floats

__global__ __launch_bounds__(256) void aggregate_pool(const unsigned* __restrict__ Tb2,
                                                      const int* __restrict__ degw,
                                                      const int* __restrict__ col_src,
                                                      const float* __restrict__ bias,
                                                      const int* __restrict__ batch,
                                                      float* __restrict__ pooled, int n,
                                                      int nzero) {
  __shared__ float sP[64][SPP];  // 33 KB
  int tid = threadIdx.x;
  int g = tid >> 4, l4 = tid & 15;
  int base = blockIdx.x * 64;
  int nb = base + g * 4;
  int nd[4]; int4 cw[4];
#pragma unroll
  for (int c = 0; c < 4; ++c) {
    int node = nb + c;
    nd[c] = node < n ? node : (n - 1);
    cw[c] = *(const int4*)&degw[(size_t)nd[c] * 4];
  }
  float acc[4][8];
  agg_quad(Tb2, col_src, cw, nd, l4, nzero, acc);

  float4 bs0 = *(const float4*)&bias[l4 * 8];
  float4 bs1 = *(const float4*)&bias[l4 * 8 + 4];
#pragma unroll
  for (int c = 0; c < 4; ++c) {
    int deg = cw[c].x + cw[c].y + cw[c].z + cw[c].w;
    float di = rsqrtf((float)deg + 1.0f);
    float o0 = fmaxf(di * acc[c][0] + bs0.x, 0.f);
    float o1 = fmaxf(di * acc[c][1] + bs0.y, 0.f);
    float o2 = fmaxf(di * acc[c][2] + bs0.z, 0.f);
    float o3 = fmaxf(di * acc[c][3] + bs0.w, 0.f);
    float o4 = fmaxf(di * acc[c][4] + bs1.x, 0.f);
    float o5 = fmaxf(di * acc[c][5] + bs1.y, 0.f);
    float o6 = fmaxf(di * acc[c][6] + bs1.z, 0.f);
    float o7 = fmaxf(di * acc[c][7] + bs1.w, 0.f);
    int nl = g * 4 + c;
    *(float4*)&sP[nl][l4 * 8] = make_float4(o0, o1, o2, o3);
    *(float4*)&sP[nl][l4 * 8 + 4] = make_float4(o4, o5, o6, o7);
  }
  __syncthreads();

  // scan 64 nodes: half h (tid>>7) covers rows h*32 .. h*32+31, feature = tid&127
  {
    int f = tid & 127;
    int h = tid >> 7;
    int i0 = h * 32, i1 = i0 + 32;
    int gq = -1;
    float accv = 0.f;
    for (int i = i0; i < i1; ++i) {
      int ndl = base + i;
      if (ndl >= n) break;
      int bi = batch[ndl];
      if (bi != gq) {
        if (gq >= 0) atomicAdd(&pooled[gq * HID + f], accv);
        accv = 0.f;
        gq = bi;
      }
      accv += sP[i][f];
    }
    if (gq >= 0) atomicAdd(&pooled[gq * HID + f], accv);
  }
}

__global__ __launch_bounds__(128) void classify_k(const float* __restrict__ pooled,
                                                  const int* __restrict__ batch,
                                                  const float* __restrict__ Wl,
                                                  const float* __restrict__ bl,
                                                  float* __restrict__ out, int n) {
  int g = blockIdx.x;
  int t = threadIdx.x;
  int lo = 0, hi = n;
  while (lo < hi) { int mid = (lo + hi) >> 1; if (batch[mid] < g) lo = mid + 1; else hi = mid; }
  int s = lo;
  hi = n;
  while (lo < hi) { int mid = (lo + hi) >> 1; if (batch[mid] < g + 1) lo = mid + 1; else hi = mid; }
  float c = fmaxf((float)(lo - s), 1.0f);
  __shared__ float p[HID];
  p[t] = pooled[g * HID + t] / c;
  __syncthreads();
  if (t < CLS) {
    float o = bl[t];
    for (int j = 0; j < HID; ++j) o += p[j] * Wl[j * CLS + t];
    out[g * CLS + t] = o;
  }
}

// ---------------- launch ----------------

extern "C" void kernel_launch(void* const* d_in, const int* in_sizes, int n_in,
                              void* d_out, int out_size, void* d_ws, size_t ws_size,
                              hipStream_t stream) {
  const float* x  = (const float*)d_in[0];
  const float* W1 = (const float*)d_in[1];
  const float* b1 = (const float*)d_in[2];
  const float* W2 = (const float*)d_in[3];
  const float* b2 = (const float*)d_in[4];
  const float* W3 = (const float*)d_in[5];
  const float* b3 = (const float*)d_in[6];
  const float* Wl = (const float*)d_in[7];
  const float* bl = (const float*)d_in[8];
  const int* edge_index = (const int*)d_in[9];
  const int* batch = (const int*)d_in[10];

  const int N = in_sizes[10];
  const int E = in_sizes[9] / 2;
  const int G = out_size / CLS;
  const int* src = edge_index;
  const int* dst = edge_index + E;

  uintptr_t p = (uintptr_t)d_ws;
  auto take = [&](size_t bytes) -> void* {
    void* r = (void*)p;
    p += (bytes + 255) & ~(size_t)255;
    return r;
  };
  int*      degw      = (int*)take((size_t)N * 4 * 4);          // [N][4] bucket counts
  int*      col_src   = (int*)take((size_t)N * NSTR * 4);       // bucketed CSR, 19.2 MB
  unsigned short* WtA = (unsigned short*)take((size_t)3 * HID * HID * 2);
  unsigned short* bufTb = (unsigned short*)take((size_t)(N + 1) * HID * 2);  // +1 zero row
  unsigned* bufHb     = (unsigned*)take((size_t)N * 64 * 4);
  float*    pooled    = (float*)take((size_t)G * HID * 4);

  int nbN = (N + 255) / 256;
  int nbE = (E + 255) / 256;
  float wscale = (float)NW / (float)N;

  zero_wt<<<nbN + 48, 256, 0, stream>>>(degw, N, nbN, pooled, G * HID, W1, W2, W3, WtA,
                                        bufTb + (size_t)N * HID);
  degree_fill<<<nbE, 256, 0, stream>>>(src, dst, degw, col_src, E, wscale);

  int gemmBlocks = (N + 127) / 128;
  int aggBlocks = (N + 63) / 64;   // 64 nodes per 256-thr block

  gemm_mfma<<<gemmBlocks, 256, 0, stream>>>(x, 1, WtA, degw, bufTb, col_src, N);
  aggregate<<<aggBlocks, 256, 0, stream>>>((unsigned*)bufTb, degw, col_src, b1, bufHb, N, N);
  gemm_mfma<<<gemmBlocks, 256, 0, stream>>>(bufHb, 0, WtA + (size_t)HID * HID, degw, bufTb,
                                            nullptr, N);
  aggregate<<<aggBlocks, 256, 0, stream>>>((unsigned*)bufTb, degw, col_src, b2, bufHb, N, N);
  gemm_mfma<<<gemmBlocks, 256, 0, stream>>>(bufHb, 0, WtA + (size_t)2 * HID * HID, degw, bufTb,
                                            nullptr, N);
  aggregate_pool<<<aggBlocks, 256, 0, stream>>>((unsigned*)bufTb, degw, col_src, b3,
                                                batch, pooled, N, N);
  classify_k<<<G, 128, 0, stream>>>(pooled, batch, Wl, bl, (float*)d_out, N);
}

// Round 5
// 271.110 us; speedup vs baseline: 1.0690x; 1.0690x over previous
//
#include <hip/hip_runtime.h>

#define HID 128
#define CLS 10
#define NW 4      // source windows (each ~N/4 nodes * 256B = 3.2MB, fits 4MiB per-XCD L2)
#define BCAP 24   // per-bucket CSR capacity; deg/window ~ Poisson(3), P(>24) ~ 1e-15
#define NSTR (NW * BCAP)  // 96 ints per node

typedef short short8 __attribute__((ext_vector_type(8)));
typedef float f32x4 __attribute__((ext_vector_type(4)));

// float -> bf16 round-to-nearest-even
__device__ __forceinline__ unsigned short f2bf(float f) {
  union { float f; unsigned u; } v; v.f = f;
  unsigned u = v.u;
  return (unsigned short)((u + 0x7FFFu + ((u >> 16) & 1u)) >> 16);
}
__device__ __forceinline__ float bf_lo(unsigned p) { return __uint_as_float(p << 16); }
__device__ __forceinline__ float bf_hi(unsigned p) { return __uint_as_float(p & 0xFFFF0000u); }

// ---------------- setup: zero degw + pooled + Tb zero-row, build Wt ----------------

__global__ __launch_bounds__(256) void zero_wt(int* __restrict__ degw, int n, int nbN,
                                               float* __restrict__ pooled, int gh,
                                               const float* __restrict__ W1,
                                               const float* __restrict__ W2,
                                               const float* __restrict__ W3,
                                               unsigned short* __restrict__ Wt,
                                               unsigned short* __restrict__ TbZeroRow) {
  int b = blockIdx.x;
  if (b < nbN) {
    int i = b * 256 + threadIdx.x;
    if (i < n) { int4 z4; z4.x = z4.y = z4.z = z4.w = 0; *(int4*)&degw[(size_t)i * 4] = z4; }
    if (i < gh) pooled[i] = 0.f;
    if (b == 0 && threadIdx.x < 16) {  // zero the dummy row (index N) of Tb: 256 B
      uint4 z; z.x = z.y = z.z = z.w = 0u;
      *(uint4*)&TbZeroRow[threadIdx.x * 8] = z;
    }
    return;
  }
  int wb = b - nbN;                  // 0..47
  int mat = wb >> 4;                 // 0..2
  int part = wb & 15;                // 0..15
  const float* W = (mat == 0) ? W1 : (mat == 1) ? W2 : W3;
  unsigned short* o = Wt + (size_t)mat * HID * HID;
  int base = part * (HID * HID / 16);
  for (int r = 0; r < HID * HID / 16; r += 256) {
    int idx = base + r + threadIdx.x;
    int k = idx >> 7, nn = idx & 127;
    o[nn * HID + k] = f2bf(W[idx]);   // Wt[n][k] = W[k][n]
  }
}

// degree histogram (per source-window bucket) + bucketed padded-CSR fill in one pass
__global__ __launch_bounds__(256) void degree_fill(const int* __restrict__ src,
                                                   const int* __restrict__ dst,
                                                   int* __restrict__ degw,
                                                   int* __restrict__ col_src, int E,
                                                   float wscale) {
  int e = blockIdx.x * 256 + threadIdx.x;
  if (e >= E) return;
  int s = src[e];
  int d = dst[e];
  int w = (int)((float)s * wscale);
  if (w > NW - 1) w = NW - 1;
  int slot = atomicAdd(&degw[(size_t)d * 4 + w], 1);
  if (slot < BCAP) col_src[(size_t)d * NSTR + w * BCAP + slot] = s;
}

// ---------------- MFMA bf16 GEMM: Tb[r,:] = bf16( dinv[r] * (A[r,:] @ W) ) ----------------

#define WTP 136  // 128 + 8 pad

__global__ __launch_bounds__(256) void gemm_mfma(const void* __restrict__ Aptr,
                                                 int a_fp32,
                                                 const unsigned short* __restrict__ Wt,  // bf16 [n][k]
                                                 const int* __restrict__ degw,
                                                 unsigned short* __restrict__ Tb,  // bf16 [n][128]
                                                 int* __restrict__ pad_col,
                                                 int nrows) {
  __shared__ unsigned short sW[HID][WTP];
  int tid = threadIdx.x;
  int wave = tid >> 6, lane = tid & 63;
  int m_lo = lane & 15, quad = lane >> 4;
  int row0 = blockIdx.x * 128;
  int rbase = row0 + wave * 32;

  uint4 araw[2][4];
#pragma unroll
  for (int tr = 0; tr < 2; ++tr) {
    int grow = rbase + tr * 16 + m_lo;
    int gr = (grow < nrows) ? grow : (nrows - 1);  // clamp: stores guarded later
    if (a_fp32) {
      const float* Arow = (const float*)Aptr + (size_t)gr * HID;
#pragma unroll
      for (int kb = 0; kb < 4; ++kb) {
        float4 f0 = *(const float4*)&Arow[kb * 32 + quad * 8];
        float4 f1 = *(const float4*)&Arow[kb * 32 + quad * 8 + 4];
        uint4 u;
        u.x = (unsigned)f2bf(f0.x) | ((unsigned)f2bf(f0.y) << 16);
        u.y = (unsigned)f2bf(f0.z) | ((unsigned)f2bf(f0.w) << 16);
        u.z = (unsigned)f2bf(f1.x) | ((unsigned)f2bf(f1.y) << 16);
        u.w = (unsigned)f2bf(f1.z) | ((unsigned)f2bf(f1.w) << 16);
        araw[tr][kb] = u;
      }
    } else {
      const uint4* Arow = (const uint4*)((const unsigned*)Aptr + (size_t)gr * 64);
#pragma unroll
      for (int kb = 0; kb < 4; ++kb) araw[tr][kb] = Arow[kb * 4 + quad];
    }
  }

  const uint4* Wt4 = (const uint4*)Wt;
#pragma unroll
  for (int i = 0; i < 8; ++i) {
    int idx = i * 256 + tid;
    *(uint4*)&sW[idx >> 4][(idx & 15) * 8] = Wt4[idx];
  }
  __syncthreads();

  f32x4 acc[2][8];
#pragma unroll
  for (int tr = 0; tr < 2; ++tr)
#pragma unroll
    for (int tc = 0; tc < 8; ++tc) acc[tr][tc] = (f32x4)(0.f);

#pragma unroll
  for (int kb = 0; kb < 4; ++kb) {
    short8 b[8];
#pragma unroll
    for (int tc = 0; tc < 8; ++tc) {
      union { uint4 u; short8 s; } cv;
      cv.u = *(const uint4*)&sW[tc * 16 + m_lo][kb * 32 + quad * 8];
      b[tc] = cv.s;
    }
#pragma unroll
    for (int tr = 0; tr < 2; ++tr) {
      union { uint4 u; short8 s; } av;
      av.u = araw[tr][kb];
#pragma unroll
      for (int tc = 0; tc < 8; ++tc)
        acc[tr][tc] = __builtin_amdgcn_mfma_f32_16x16x32_bf16(av.s, b[tc], acc[tr][tc], 0, 0, 0);
    }
  }

#pragma unroll
  for (int tr = 0; tr < 2; ++tr) {
#pragma unroll
    for (int r = 0; r < 4; ++r) {
      int grow = rbase + tr * 16 + quad * 4 + r;
      if (grow < nrows) {
        int4 cwv = *(const int4*)&degw[(size_t)grow * 4];
        int dgv = cwv.x + cwv.y + cwv.z + cwv.w;
        float s = rsqrtf((float)dgv + 1.0f);  // dinv inline
        unsigned short* orow = &Tb[(size_t)grow * HID];
#pragma unroll
        for (int tc = 0; tc < 8; ++tc)
          orow[tc * 16 + m_lo] = f2bf(s * acc[tr][tc][r]);
        if (pad_col && m_lo == 0) {
#pragma unroll
          for (int w = 0; w < NW; ++w) {
            int cc = (w == 0) ? cwv.x : (w == 1) ? cwv.y : (w == 2) ? cwv.z : cwv.w;
            int d = cc < BCAP ? cc : BCAP;
            int dp = (d + 3) & ~3;
            for (int sl = d; sl < dp; ++sl)
              pad_col[(size_t)grow * NSTR + w * BCAP + sl] = nrows;  // dummy -> zero row
          }
        }
      }
    }
  }
}

// ---------------- aggregate core: window-phased, 2 nodes per 16-lane group ----------------
// Block = 32 consecutive nodes (16 groups x 2 nodes) -> 1563 blocks (~6 co-resident
// blocks/CU, vs R3's 3 which starved concurrency). All blocks sweep source windows
// w=0..3 in the same order; co-running blocks stay roughly phase-aligned so gathers
// concentrate in a ~3.2MB Tb window resident in each XCD's 4MiB L2 (R3 measured
// FETCH 56MB = ~67% L2 hit). Node pairs -> 8 gathers in flight per group (32/wave).

__device__ __forceinline__ void accum_row(float a[8], uint4 v) {
  a[0] += bf_lo(v.x); a[1] += bf_hi(v.x);
  a[2] += bf_lo(v.y); a[3] += bf_hi(v.y);
  a[4] += bf_lo(v.z); a[5] += bf_hi(v.z);
  a[6] += bf_lo(v.w); a[7] += bf_hi(v.w);
}

__device__ __forceinline__ uint4 tb_row(const unsigned* __restrict__ Tb2, int idx, int l4) {
  return *(const uint4*)&Tb2[(size_t)idx * 64 + l4 * 4];
}

__device__ __forceinline__ int cw_get(int4 v, int w) {
  return (w == 0) ? v.x : (w == 1) ? v.y : (w == 2) ? v.z : v.w;
}

__device__ __forceinline__ void agg_pair(const unsigned* __restrict__ Tb2,
                                         const int* __restrict__ col_src,
                                         const int4 cw[2], const int nd[2], int l4,
                                         int nzero, float acc[2][8]) {
#pragma unroll
  for (int c = 0; c < 2; ++c) {  // self-loop rows (init accumulators)
    uint4 sv = tb_row(Tb2, nd[c], l4);
    acc[c][0] = bf_lo(sv.x); acc[c][1] = bf_hi(sv.x);
    acc[c][2] = bf_lo(sv.y); acc[c][3] = bf_hi(sv.y);
    acc[c][4] = bf_lo(sv.z); acc[c][5] = bf_hi(sv.z);
    acc[c][6] = bf_lo(sv.w); acc[c][7] = bf_hi(sv.w);
  }
#pragma unroll
  for (int w = 0; w < NW; ++w) {
    int n0 = cw_get(cw[0], w); n0 = n0 < BCAP ? n0 : BCAP;
    int n1 = cw_get(cw[1], w); n1 = n1 < BCAP ? n1 : BCAP;
    int dp0 = (n0 + 3) & ~3, dp1 = (n1 + 3) & ~3;
    const int* r0 = &col_src[(size_t)nd[0] * NSTR + w * BCAP];
    const int* r1 = &col_src[(size_t)nd[1] * NSTR + w * BCAP];
    int4 i0 = (dp0 > 0) ? *(const int4*)r0 : make_int4(nzero, nzero, nzero, nzero);
    int4 i1 = (dp1 > 0) ? *(const int4*)r1 : make_int4(nzero, nzero, nzero, nzero);
    uint4 v0[4], v1[4];
    v0[0] = tb_row(Tb2, i0.x, l4); v0[1] = tb_row(Tb2, i0.y, l4);
    v0[2] = tb_row(Tb2, i0.z, l4); v0[3] = tb_row(Tb2, i0.w, l4);
    v1[0] = tb_row(Tb2, i1.x, l4); v1[1] = tb_row(Tb2, i1.y, l4);
    v1[2] = tb_row(Tb2, i1.z, l4); v1[3] = tb_row(Tb2, i1.w, l4);
#pragma unroll
    for (int u = 0; u < 4; ++u) accum_row(acc[0], v0[u]);
#pragma unroll
    for (int u = 0; u < 4; ++u) accum_row(acc[1], v1[u]);
    for (int j = 4; j < dp0; j += 4) {  // ~18% of buckets: count > 4
      int4 ii = *(const int4*)(r0 + j);
      uint4 a0 = tb_row(Tb2, ii.x, l4), a1 = tb_row(Tb2, ii.y, l4);
      uint4 a2 = tb_row(Tb2, ii.z, l4), a3 = tb_row(Tb2, ii.w, l4);
      accum_row(acc[0], a0); accum_row(acc[0], a1);
      accum_row(acc[0], a2); accum_row(acc[0], a3);
    }
    for (int j = 4; j < dp1; j += 4) {
      int4 ii = *(const int4*)(r1 + j);
      uint4 a0 = tb_row(Tb2, ii.x, l4), a1 = tb_row(Tb2, ii.y, l4);
      uint4 a2 = tb_row(Tb2, ii.z, l4), a3 = tb_row(Tb2, ii.w, l4);
      accum_row(acc[1], a0); accum_row(acc[1], a1);
      accum_row(acc[1], a2); accum_row(acc[1], a3);
    }
  }
}

// layers 1,2: write packed bf16 H (consumed by next GEMM); nontemporal stores so
// the 12.8MB output stream does not evict the L2-resident source window.
__global__ __launch_bounds__(256) void aggregate(const unsigned* __restrict__ Tb2,
                                                 const int* __restrict__ degw,
                                                 const int* __restrict__ col_src,
                                                 const float* __restrict__ bias,
                                                 unsigned* __restrict__ Hb, int n, int nzero) {
  int tid = threadIdx.x;
  int g = tid >> 4, l4 = tid & 15;
  int base = blockIdx.x * 32 + g * 2;
  int nd[2]; int4 cw[2];
#pragma unroll
  for (int c = 0; c < 2; ++c) {
    int node = base + c;
    nd[c] = node < n ? node : (n - 1);
    cw[c] = *(const int4*)&degw[(size_t)nd[c] * 4];
  }
  float acc[2][8];
  agg_pair(Tb2, col_src, cw, nd, l4, nzero, acc);

  float4 bs0 = *(const float4*)&bias[l4 * 8];
  float4 bs1 = *(const float4*)&bias[l4 * 8 + 4];
#pragma unroll
  for (int c = 0; c < 2; ++c) {
    int node = base + c;
    if (node < n) {
      int deg = cw[c].x + cw[c].y + cw[c].z + cw[c].w;
      float di = rsqrtf((float)deg + 1.0f);
      float o0 = fmaxf(di * acc[c][0] + bs0.x, 0.f);
      float o1 = fmaxf(di * acc[c][1] + bs0.y, 0.f);
      float o2 = fmaxf(di * acc[c][2] + bs0.z, 0.f);
      float o3 = fmaxf(di * acc[c][3] + bs0.w, 0.f);
      float o4 = fmaxf(di * acc[c][4] + bs1.x, 0.f);
      float o5 = fmaxf(di * acc[c][5] + bs1.y, 0.f);
      float o6 = fmaxf(di * acc[c][6] + bs1.z, 0.f);
      float o7 = fmaxf(di * acc[c][7] + bs1.w, 0.f);
      union { uint4 u4; unsigned long long ll[2]; } o;
      o.u4.x = (unsigned)f2bf(o0) | ((unsigned)f2bf(o1) << 16);
      o.u4.y = (unsigned)f2bf(o2) | ((unsigned)f2bf(o3) << 16);
      o.u4.z = (unsigned)f2bf(o4) | ((unsigned)f2bf(o5) << 16);
      o.u4.w = (unsigned)f2bf(o6) | ((unsigned)f2bf(o7) << 16);
      unsigned long long* dst = (unsigned long long*)&Hb[(size_t)node * 64 + l4 * 4];
      __builtin_nontemporal_store(o.ll[0], dst);
      __builtin_nontemporal_store(o.ll[1], dst + 1);
    }
  }
}

// layer 3: no Hb output; pool directly (block = 32 consecutive nodes, run-detected
// atomics into pooled; scan split across two 128-lane halves)
#define SPP 132  // 128 + 4 pad floats

__global__ __launch_bounds__(256) void aggregate_pool(const unsigned* __restrict__ Tb2,
                                                      const int* __restrict__ degw,
                                                      const int* __restrict__ col_src,
                                                      const float* __restrict__ bias,
                                                      const int* __restrict__ batch,
                                                      float* __restrict__ pooled, int n,
                                                      int nzero) {
  __shared__ float sP[32][SPP];  // 16.5 KB
  int tid = threadIdx.x;
  int g = tid >> 4, l4 = tid & 15;
  int base = blockIdx.x * 32;
  int nb = base + g * 2;
  int nd[2]; int4 cw[2];
#pragma unroll
  for (int c = 0; c < 2; ++c) {
    int node = nb + c;
    nd[c] = node < n ? node : (n - 1);
    cw[c] = *(const int4*)&degw[(size_t)nd[c] * 4];
  }
  float acc[2][8];
  agg_pair(Tb2, col_src, cw, nd, l4, nzero, acc);

  float4 bs0 = *(const float4*)&bias[l4 * 8];
  float4 bs1 = *(const float4*)&bias[l4 * 8 + 4];
#pragma unroll
  for (int c = 0; c < 2; ++c) {
    int deg = cw[c].x + cw[c].y + cw[c].z + cw[c].w;
    float di = rsqrtf((float)deg + 1.0f);
    float o0 = fmaxf(di * acc[c][0] + bs0.x, 0.f);
    float o1 = fmaxf(di * acc[c][1] + bs0.y, 0.f);
    float o2 = fmaxf(di * acc[c][2] + bs0.z, 0.f);
    float o3 = fmaxf(di * acc[c][3] + bs0.w, 0.f);
    float o4 = fmaxf(di * acc[c][4] + bs1.x, 0.f);
    float o5 = fmaxf(di * acc[c][5] + bs1.y, 0.f);
    float o6 = fmaxf(di * acc[c][6] + bs1.z, 0.f);
    float o7 = fmaxf(di * acc[c][7] + bs1.w, 0.f);
    int nl = g * 2 + c;
    *(float4*)&sP[nl][l4 * 8] = make_float4(o0, o1, o2, o3);
    *(float4*)&sP[nl][l4 * 8 + 4] = make_float4(o4, o5, o6, o7);
  }
  __syncthreads();

  // scan 32 nodes: half h (tid>>7) covers rows h*16 .. h*16+15, feature = tid&127
  {
    int f = tid & 127;
    int h = tid >> 7;
    int i0 = h * 16, i1 = i0 + 16;
    int gq = -1;
    float accv = 0.f;
    for (int i = i0; i < i1; ++i) {
      int ndl = base + i;
      if (ndl >= n) break;
      int bi = batch[ndl];
      if (bi != gq) {
        if (gq >= 0) atomicAdd(&pooled[gq * HID + f], accv);
        accv = 0.f;
        gq = bi;
      }
      accv += sP[i][f];
    }
    if (gq >= 0) atomicAdd(&pooled[gq * HID + f], accv);
  }
}

__global__ __launch_bounds__(128) void classify_k(const float* __restrict__ pooled,
                                                  const int* __restrict__ batch,
                                                  const float* __restrict__ Wl,
                                                  const float* __restrict__ bl,
                                                  float* __restrict__ out, int n) {
  int g = blockIdx.x;
  int t = threadIdx.x;
  int lo = 0, hi = n;
  while (lo < hi) { int mid = (lo + hi) >> 1; if (batch[mid] < g) lo = mid + 1; else hi = mid; }
  int s = lo;
  hi = n;
  while (lo < hi) { int mid = (lo + hi) >> 1; if (batch[mid] < g + 1) lo = mid + 1; else hi = mid; }
  float c = fmaxf((float)(lo - s), 1.0f);
  __shared__ float p[HID];
  p[t] = pooled[g * HID + t] / c;
  __syncthreads();
  if (t < CLS) {
    float o = bl[t];
    for (int j = 0; j < HID; ++j) o += p[j] * Wl[j * CLS + t];
    out[g * CLS + t] = o;
  }
}

// ---------------- launch ----------------

extern "C" void kernel_launch(void* const* d_in, const int* in_sizes, int n_in,
                              void* d_out, int out_size, void* d_ws, size_t ws_size,
                              hipStream_t stream) {
  const float* x  = (const float*)d_in[0];
  const float* W1 = (const float*)d_in[1];
  const float* b1 = (const float*)d_in[2];
  const float* W2 = (const float*)d_in[3];
  const float* b2 = (const float*)d_in[4];
  const float* W3 = (const float*)d_in[5];
  const float* b3 = (const float*)d_in[6];
  const float* Wl = (const float*)d_in[7];
  const float* bl = (const float*)d_in[8];
  const int* edge_index = (const int*)d_in[9];
  const int* batch = (const int*)d_in[10];

  const int N = in_sizes[10];
  const int E = in_sizes[9] / 2;
  const int G = out_size / CLS;
  const int* src = edge_index;
  const int* dst = edge_index + E;

  uintptr_t p = (uintptr_t)d_ws;
  auto take = [&](size_t bytes) -> void* {
    void* r = (void*)p;
    p += (bytes + 255) & ~(size_t)255;
    return r;
  };
  int*      degw      = (int*)take((size_t)N * 4 * 4);          // [N][4] bucket counts
  int*      col_src   = (int*)take((size_t)N * NSTR * 4);       // bucketed CSR, 19.2 MB
  unsigned short* WtA = (unsigned short*)take((size_t)3 * HID * HID * 2);
  unsigned short* bufTb = (unsigned short*)take((size_t)(N + 1) * HID * 2);  // +1 zero row
  unsigned* bufHb     = (unsigned*)take((size_t)N * 64 * 4);
  float*    pooled    = (float*)take((size_t)G * HID * 4);

  int nbN = (N + 255) / 256;
  int nbE = (E + 255) / 256;
  float wscale = (float)NW / (float)N;

  zero_wt<<<nbN + 48, 256, 0, stream>>>(degw, N, nbN, pooled, G * HID, W1, W2, W3, WtA,
                                        bufTb + (size_t)N * HID);
  degree_fill<<<nbE, 256, 0, stream>>>(src, dst, degw, col_src, E, wscale);

  int gemmBlocks = (N + 127) / 128;
  int aggBlocks = (N + 31) / 32;   // 32 nodes per 256-thr block -> 1563 blocks

  gemm_mfma<<<gemmBlocks, 256, 0, stream>>>(x, 1, WtA, degw, bufTb, col_src, N);
  aggregate<<<aggBlocks, 256, 0, stream>>>((unsigned*)bufTb, degw, col_src, b1, bufHb, N, N);
  gemm_mfma<<<gemmBlocks, 256, 0, stream>>>(bufHb, 0, WtA + (size_t)HID * HID, degw, bufTb,
                                            nullptr, N);
  aggregate<<<aggBlocks, 256, 0, stream>>>((unsigned*)bufTb, degw, col_src, b2, bufHb, N, N);
  gemm_mfma<<<gemmBlocks, 256, 0, stream>>>(bufHb, 0, WtA + (size_t)2 * HID * HID, degw, bufTb,
                                            nullptr, N);
  aggregate_pool<<<aggBlocks, 256, 0, stream>>>((unsigned*)bufTb, degw, col_src, b3,
                                                batch, pooled, N, N);
  classify_k<<<G, 128, 0, stream>>>(pooled, batch, Wl, bl, (float*)d_out, N);
}

// Round 6
// 227.411 us; speedup vs baseline: 1.2744x; 1.1922x over previous
//
#include <hip/hip_runtime.h>

#define HID 128
#define CLS 10
#define RCAP 64  // padded CSR row capacity; deg ~ Poisson(12), P(>=64) ~ 1e-34

typedef short short8 __attribute__((ext_vector_type(8)));
typedef float f32x4 __attribute__((ext_vector_type(4)));

// float -> bf16 round-to-nearest-even
__device__ __forceinline__ unsigned short f2bf(float f) {
  union { float f; unsigned u; } v; v.f = f;
  unsigned u = v.u;
  return (unsigned short)((u + 0x7FFFu + ((u >> 16) & 1u)) >> 16);
}
__device__ __forceinline__ float bf_lo(unsigned p) { return __uint_as_float(p << 16); }
__device__ __forceinline__ float bf_hi(unsigned p) { return __uint_as_float(p & 0xFFFF0000u); }

// ---------------- setup: zero degi + pooled + both T zero-rows, build Wt ----------------

__global__ __launch_bounds__(256) void zero_wt(int* __restrict__ degi, int n, int nbN,
                                               float* __restrict__ pooled, int gh,
                                               const float* __restrict__ W1,
                                               const float* __restrict__ W2,
                                               const float* __restrict__ W3,
                                               unsigned short* __restrict__ Wt,
                                               unsigned short* __restrict__ TzA,
                                               unsigned short* __restrict__ TzB) {
  int b = blockIdx.x;
  if (b < nbN) {
    int i = b * 256 + threadIdx.x;
    if (i < n) degi[i] = 0;
    if (i < gh) pooled[i] = 0.f;
    if (b == 0 && threadIdx.x < 16) {  // zero dummy rows (index N) of both T buffers
      uint4 z; z.x = z.y = z.z = z.w = 0u;
      *(uint4*)&TzA[threadIdx.x * 8] = z;
      *(uint4*)&TzB[threadIdx.x * 8] = z;
    }
    return;
  }
  int wb = b - nbN;                  // 0..47
  int mat = wb >> 4;                 // 0..2
  int part = wb & 15;                // 0..15
  const float* W = (mat == 0) ? W1 : (mat == 1) ? W2 : W3;
  unsigned short* o = Wt + (size_t)mat * HID * HID;
  int base = part * (HID * HID / 16);
  for (int r = 0; r < HID * HID / 16; r += 256) {
    int idx = base + r + threadIdx.x;
    int k = idx >> 7, nn = idx & 127;
    o[nn * HID + k] = f2bf(W[idx]);   // Wt[n][k] = W[k][n]
  }
}

// degree histogram + padded-CSR fill in one pass
__global__ __launch_bounds__(256) void degree_fill(const int* __restrict__ src,
                                                   const int* __restrict__ dst,
                                                   int* __restrict__ degi,
                                                   int* __restrict__ col_src, int E) {
  int e = blockIdx.x * 256 + threadIdx.x;
  if (e >= E) return;
  int d = dst[e];
  int slot = atomicAdd(&degi[d], 1);
  if (slot < RCAP) col_src[(size_t)d * RCAP + slot] = src[e];
}

// ---------------- MFMA bf16 GEMM (layer 1): Tb[r,:] = bf16( dinv[r] * (x[r,:] @ W) ) ----
// Block = 4 waves x 32 rows = 128 rows. W staged in LDS; A fragments direct
// global->VGPR (fp32 x converted in-register). Also pads each CSR row to a
// multiple of 4 with dummy index `nrows` (the zero row) - persistent for all layers.

#define WTP 136  // 128 + 8 pad

__global__ __launch_bounds__(256) void gemm_mfma(const float* __restrict__ Aptr,
                                                 const unsigned short* __restrict__ Wt,  // bf16 [n][k]
                                                 const int* __restrict__ degi,
                                                 unsigned short* __restrict__ Tb,  // bf16 [n][128]
                                                 int* __restrict__ pad_col,
                                                 int nrows) {
  __shared__ unsigned short sW[HID][WTP];
  int tid = threadIdx.x;
  int wave = tid >> 6, lane = tid & 63;
  int m_lo = lane & 15, quad = lane >> 4;
  int row0 = blockIdx.x * 128;
  int rbase = row0 + wave * 32;

  uint4 araw[2][4];
#pragma unroll
  for (int tr = 0; tr < 2; ++tr) {
    int grow = rbase + tr * 16 + m_lo;
    int gr = (grow < nrows) ? grow : (nrows - 1);  // clamp: stores guarded later
    const float* Arow = Aptr + (size_t)gr * HID;
#pragma unroll
    for (int kb = 0; kb < 4; ++kb) {
      float4 f0 = *(const float4*)&Arow[kb * 32 + quad * 8];
      float4 f1 = *(const float4*)&Arow[kb * 32 + quad * 8 + 4];
      uint4 u;
      u.x = (unsigned)f2bf(f0.x) | ((unsigned)f2bf(f0.y) << 16);
      u.y = (unsigned)f2bf(f0.z) | ((unsigned)f2bf(f0.w) << 16);
      u.z = (unsigned)f2bf(f1.x) | ((unsigned)f2bf(f1.y) << 16);
      u.w = (unsigned)f2bf(f1.z) | ((unsigned)f2bf(f1.w) << 16);
      araw[tr][kb] = u;
    }
  }

  const uint4* Wt4 = (const uint4*)Wt;
#pragma unroll
  for (int i = 0; i < 8; ++i) {
    int idx = i * 256 + tid;
    *(uint4*)&sW[idx >> 4][(idx & 15) * 8] = Wt4[idx];
  }
  __syncthreads();

  f32x4 acc[2][8];
#pragma unroll
  for (int tr = 0; tr < 2; ++tr)
#pragma unroll
    for (int tc = 0; tc < 8; ++tc) acc[tr][tc] = (f32x4)(0.f);

#pragma unroll
  for (int kb = 0; kb < 4; ++kb) {
    short8 b[8];
#pragma unroll
    for (int tc = 0; tc < 8; ++tc) {
      union { uint4 u; short8 s; } cv;
      cv.u = *(const uint4*)&sW[tc * 16 + m_lo][kb * 32 + quad * 8];
      b[tc] = cv.s;
    }
#pragma unroll
    for (int tr = 0; tr < 2; ++tr) {
      union { uint4 u; short8 s; } av;
      av.u = araw[tr][kb];
#pragma unroll
      for (int tc = 0; tc < 8; ++tc)
        acc[tr][tc] = __builtin_amdgcn_mfma_f32_16x16x32_bf16(av.s, b[tc], acc[tr][tc], 0, 0, 0);
    }
  }

#pragma unroll
  for (int tr = 0; tr < 2; ++tr) {
#pragma unroll
    for (int r = 0; r < 4; ++r) {
      int grow = rbase + tr * 16 + quad * 4 + r;
      if (grow < nrows) {
        int dgv = degi[grow];
        float s = rsqrtf((float)dgv + 1.0f);  // dinv inline
        unsigned short* orow = &Tb[(size_t)grow * HID];
#pragma unroll
        for (int tc = 0; tc < 8; ++tc)
          orow[tc * 16 + m_lo] = f2bf(s * acc[tr][tc][r]);
        if (m_lo == 0) {
          int d = dgv < RCAP ? dgv : RCAP;
          int dp = (d + 3) & ~3;
          for (int sl = d; sl < dp; ++sl)
            pad_col[(size_t)grow * RCAP + sl] = nrows;  // dummy -> zero row
        }
      }
    }
  }
}

// ---------------- aggregate core (R2-proven): 16-lane group per node ----------------
// CSR rows padded to x4 with the zero-row index: pure 8/4-chunks, 8 gathers in
// flight per group (32/wave), no scalar tail.

__device__ __forceinline__ void agg_node(const unsigned* __restrict__ Tb2,
                                         const int* __restrict__ degi,
                                         const int* __restrict__ col_src,
                                         const float* __restrict__ bias,
                                         int node, int l4, float a[8]) {
  uint4 sv = *(const uint4*)&Tb2[(size_t)node * 64 + l4 * 4];
  a[0] = bf_lo(sv.x); a[1] = bf_hi(sv.x); a[2] = bf_lo(sv.y); a[3] = bf_hi(sv.y);
  a[4] = bf_lo(sv.z); a[5] = bf_hi(sv.z); a[6] = bf_lo(sv.w); a[7] = bf_hi(sv.w);
  int deg = degi[node];
  int dc = deg < RCAP ? deg : RCAP;
  int dp = (dc + 3) & ~3;       // padded length (pad slots point at zero row)
  const int* row = &col_src[(size_t)node * RCAP];
  int j = 0;
  for (; j + 8 <= dp; j += 8) {
    int idx[8];
#pragma unroll
    for (int u = 0; u < 8; ++u) idx[u] = row[j + u];
    uint4 v[8];
#pragma unroll
    for (int u = 0; u < 8; ++u) v[u] = *(const uint4*)&Tb2[(size_t)idx[u] * 64 + l4 * 4];
#pragma unroll
    for (int u = 0; u < 8; ++u) {
      a[0] += bf_lo(v[u].x); a[1] += bf_hi(v[u].x);
      a[2] += bf_lo(v[u].y); a[3] += bf_hi(v[u].y);
      a[4] += bf_lo(v[u].z); a[5] += bf_hi(v[u].z);
      a[6] += bf_lo(v[u].w); a[7] += bf_hi(v[u].w);
    }
  }
  if (j < dp) {  // exactly one 4-chunk (dp - j == 4)
    int idx[4];
#pragma unroll
    for (int u = 0; u < 4; ++u) idx[u] = row[j + u];
    uint4 v[4];
#pragma unroll
    for (int u = 0; u < 4; ++u) v[u] = *(const uint4*)&Tb2[(size_t)idx[u] * 64 + l4 * 4];
#pragma unroll
    for (int u = 0; u < 4; ++u) {
      a[0] += bf_lo(v[u].x); a[1] += bf_hi(v[u].x);
      a[2] += bf_lo(v[u].y); a[3] += bf_hi(v[u].y);
      a[4] += bf_lo(v[u].z); a[5] += bf_hi(v[u].z);
      a[6] += bf_lo(v[u].w); a[7] += bf_hi(v[u].w);
    }
  }
  float di = rsqrtf((float)deg + 1.0f);
  float4 bs0 = *(const float4*)&bias[l4 * 8];
  float4 bs1 = *(const float4*)&bias[l4 * 8 + 4];
  a[0] = fmaxf(di * a[0] + bs0.x, 0.f);
  a[1] = fmaxf(di * a[1] + bs0.y, 0.f);
  a[2] = fmaxf(di * a[2] + bs0.z, 0.f);
  a[3] = fmaxf(di * a[3] + bs0.w, 0.f);
  a[4] = fmaxf(di * a[4] + bs1.x, 0.f);
  a[5] = fmaxf(di * a[5] + bs1.y, 0.f);
  a[6] = fmaxf(di * a[6] + bs1.z, 0.f);
  a[7] = fmaxf(di * a[7] + bs1.w, 0.f);
}

// ---------------- fused aggregate + next-layer GEMM ----------------
// Block = 16 nodes (R2 aggregate geometry). Phase 1: gather+relu -> bf16 rows in
// LDS. Phase 2: 16x128 MFMA tile vs W (staged LDS), epilogue applies next
// layer's dinv and writes T_{l+1} directly. Skips the Hb HBM round-trip, and
// the MFMA work runs on CUs whose VMEM pipes are gather-stalled (MSHR-bound).

__global__ __launch_bounds__(256, 4) void fused_agg_gemm(const unsigned* __restrict__ Tb_in,
                                                         const int* __restrict__ degi,
                                                         const int* __restrict__ col_src,
                                                         const float* __restrict__ bias,
                                                         const unsigned short* __restrict__ Wt,
                                                         unsigned short* __restrict__ Tb_out,
                                                         int n) {
  __shared__ unsigned short sW[HID][WTP];  // 34.8 KB
  __shared__ unsigned short sH[16][WTP];   // 4.3 KB
  int tid = threadIdx.x;

  // stage W (issued before gathers; completes long before the barrier)
  const uint4* Wt4 = (const uint4*)Wt;
#pragma unroll
  for (int i = 0; i < 8; ++i) {
    int idx = i * 256 + tid;
    *(uint4*)&sW[idx >> 4][(idx & 15) * 8] = Wt4[idx];
  }

  // phase 1: aggregate 16 nodes (one 16-lane group per node)
  int nl = tid >> 4, l4 = tid & 15;
  int node = blockIdx.x * 16 + nl;
  int nodec = node < n ? node : (n - 1);
  float a[8];
  agg_node(Tb_in, degi, col_src, bias, nodec, l4, a);
  uint4 o;
  o.x = (unsigned)f2bf(a[0]) | ((unsigned)f2bf(a[1]) << 16);
  o.y = (unsigned)f2bf(a[2]) | ((unsigned)f2bf(a[3]) << 16);
  o.z = (unsigned)f2bf(a[4]) | ((unsigned)f2bf(a[5]) << 16);
  o.w = (unsigned)f2bf(a[6]) | ((unsigned)f2bf(a[7]) << 16);
  *(uint4*)&sH[nl][l4 * 8] = o;
  __syncthreads();

  // phase 2: T_out[16 rows] = dinv * (sH @ W). 4 waves x 2 col-tiles each.
  int wid = tid >> 6, lane = tid & 63;
  int m_lo = lane & 15, quad = lane >> 4;
  f32x4 acc[2];
  acc[0] = (f32x4)(0.f); acc[1] = (f32x4)(0.f);
#pragma unroll
  for (int kb = 0; kb < 4; ++kb) {
    union { uint4 u; short8 s; } av;
    av.u = *(const uint4*)&sH[m_lo][kb * 32 + quad * 8];
#pragma unroll
    for (int t = 0; t < 2; ++t) {
      int tc = wid * 2 + t;
      union { uint4 u; short8 s; } bv;
      bv.u = *(const uint4*)&sW[tc * 16 + m_lo][kb * 32 + quad * 8];
      acc[t] = __builtin_amdgcn_mfma_f32_16x16x32_bf16(av.s, bv.s, acc[t], 0, 0, 0);
    }
  }
#pragma unroll
  for (int r = 0; r < 4; ++r) {
    int grow = blockIdx.x * 16 + quad * 4 + r;
    if (grow < n) {
      float s = rsqrtf((float)degi[grow] + 1.0f);
      unsigned short* orow = &Tb_out[(size_t)grow * HID];
#pragma unroll
      for (int t = 0; t < 2; ++t) {
        int tc = wid * 2 + t;
        orow[tc * 16 + m_lo] = f2bf(s * acc[t][r]);
      }
    }
  }
}

// layer 3: no T output; pool directly (block = 16 consecutive nodes, run-detected
// atomics into pooled)
#define SPP 132  // 128 + 4 pad floats

__global__ __launch_bounds__(256) void aggregate_pool(const unsigned* __restrict__ Tb2,
                                                      const int* __restrict__ degi,
                                                      const int* __restrict__ col_src,
                                                      const float* __restrict__ bias,
                                                      const int* __restrict__ batch,
                                                      float* __restrict__ pooled, int n) {
  __shared__ float sP[16][SPP];  // 8.25 KB
  int tid = threadIdx.x;
  int wave = tid >> 6, lane = tid & 63;
  int sub = lane >> 4;
  int l4 = lane & 15;
  int base = blockIdx.x * 16;
  int nl = wave * 4 + sub;       // 0..15
  int node = base + nl;
  bool active = (node < n);

  float a[8] = {0.f, 0.f, 0.f, 0.f, 0.f, 0.f, 0.f, 0.f};
  if (active) agg_node(Tb2, degi, col_src, bias, node, l4, a);
  *(float4*)&sP[nl][l4 * 8] = make_float4(a[0], a[1], a[2], a[3]);
  *(float4*)&sP[nl][l4 * 8 + 4] = make_float4(a[4], a[5], a[6], a[7]);
  __syncthreads();

  if (tid < HID) {
    int g = -1;
    float acc = 0.f;
    for (int i = 0; i < 16; ++i) {
      int nd = base + i;
      if (nd >= n) break;
      int bi = batch[nd];
      if (bi != g) {
        if (g >= 0) atomicAdd(&pooled[g * HID + tid], acc);
        acc = 0.f;
        g = bi;
      }
      acc += sP[i][tid];
    }
    if (g >= 0) atomicAdd(&pooled[g * HID + tid], acc);
  }
}

__global__ __launch_bounds__(128) void classify_k(const float* __restrict__ pooled,
                                                  const int* __restrict__ batch,
                                                  const float* __restrict__ Wl,
                                                  const float* __restrict__ bl,
                                                  float* __restrict__ out, int n) {
  int g = blockIdx.x;
  int t = threadIdx.x;
  int lo = 0, hi = n;
  while (lo < hi) { int mid = (lo + hi) >> 1; if (batch[mid] < g) lo = mid + 1; else hi = mid; }
  int s = lo;
  hi = n;
  while (lo < hi) { int mid = (lo + hi) >> 1; if (batch[mid] < g + 1) lo = mid + 1; else hi = mid; }
  float c = fmaxf((float)(lo - s), 1.0f);
  __shared__ float p[HID];
  p[t] = pooled[g * HID + t] / c;
  __syncthreads();
  if (t < CLS) {
    float o = bl[t];
    for (int j = 0; j < HID; ++j) o += p[j] * Wl[j * CLS + t];
    out[g * CLS + t] = o;
  }
}

// ---------------- launch ----------------

extern "C" void kernel_launch(void* const* d_in, const int* in_sizes, int n_in,
                              void* d_out, int out_size, void* d_ws, size_t ws_size,
                              hipStream_t stream) {
  const float* x  = (const float*)d_in[0];
  const float* W1 = (const float*)d_in[1];
  const float* b1 = (const float*)d_in[2];
  const float* W2 = (const float*)d_in[3];
  const float* b2 = (const float*)d_in[4];
  const float* W3 = (const float*)d_in[5];
  const float* b3 = (const float*)d_in[6];
  const float* Wl = (const float*)d_in[7];
  const float* bl = (const float*)d_in[8];
  const int* edge_index = (const int*)d_in[9];
  const int* batch = (const int*)d_in[10];

  const int N = in_sizes[10];
  const int E = in_sizes[9] / 2;
  const int G = out_size / CLS;
  const int* src = edge_index;
  const int* dst = edge_index + E;

  uintptr_t p = (uintptr_t)d_ws;
  auto take = [&](size_t bytes) -> void* {
    void* r = (void*)p;
    p += (bytes + 255) & ~(size_t)255;
    return r;
  };
  int*      degi      = (int*)take((size_t)N * 4);
  int*      col_src   = (int*)take((size_t)N * RCAP * 4);  // padded CSR, 12.8 MB
  unsigned short* WtA = (unsigned short*)take((size_t)3 * HID * HID * 2);
  unsigned short* bufTa = (unsigned short*)take((size_t)(N + 1) * HID * 2);  // +1 zero row
  unsigned short* bufTb = (unsigned short*)take((size_t)(N + 1) * HID * 2);  // +1 zero row
  float*    pooled    = (float*)take((size_t)G * HID * 4);

  int nbN = (N + 255) / 256;
  int nbE = (E + 255) / 256;

  zero_wt<<<nbN + 48, 256, 0, stream>>>(degi, N, nbN, pooled, G * HID, W1, W2, W3, WtA,
                                        bufTa + (size_t)N * HID, bufTb + (size_t)N * HID);
  degree_fill<<<nbE, 256, 0, stream>>>(src, dst, degi, col_src, E);

  int gemmBlocks = (N + 127) / 128;
  int aggBlocks = (N + 15) / 16;   // 16 nodes per 256-thr block

  // layer 1 GEMM: x @ W1 -> T1 (A), also pads CSR rows
  gemm_mfma<<<gemmBlocks, 256, 0, stream>>>(x, WtA, degi, bufTa, col_src, N);
  // layer 1 aggregate fused with layer 2 GEMM: T1 (A) -> T2 (B)
  fused_agg_gemm<<<aggBlocks, 256, 0, stream>>>((unsigned*)bufTa, degi, col_src, b1,
                                                WtA + (size_t)HID * HID, bufTb, N);
  // layer 2 aggregate fused with layer 3 GEMM: T2 (B) -> T3 (A)
  fused_agg_gemm<<<aggBlocks, 256, 0, stream>>>((unsigned*)bufTb, degi, col_src, b2,
                                                WtA + (size_t)2 * HID * HID, bufTa, N);
  // layer 3 aggregate + pool
  aggregate_pool<<<aggBlocks, 256, 0, stream>>>((unsigned*)bufTa, degi, col_src, b3,
                                                batch, pooled, N);
  classify_k<<<G, 128, 0, stream>>>(pooled, batch, Wl, bl, (float*)d_out, N);
}